// Round 1
// baseline (6135.870 us; speedup 1.0000x reference)
//
#include <hip/hip_runtime.h>
#include <math.h>

#define N_NODES 50000
#define N_EDGES 800000
#define IN_CH 128
#define HID 256
#define OUT_CH 40

// ---------------- tiled fp32 GEMM: C[N,M] = A[N,K] @ W[K,M] ----------------
#define BM 64
#define BN 64
#define BK 16

__global__ __launch_bounds__(256) void sgemm(const float* __restrict__ A,
                                             const float* __restrict__ W,
                                             float* __restrict__ C,
                                             int N, int K, int M) {
    // As stored transposed [k][row] so the 4x4 microtile reads are float4s.
    __shared__ __align__(16) float As[BK][BM + 4];
    __shared__ __align__(16) float Bs[BK][BN + 4];
    const int tid  = threadIdx.x;
    const int row0 = blockIdx.y * BM;
    const int col0 = blockIdx.x * BN;
    const int tx   = tid & 15;   // micro col group
    const int ty   = tid >> 4;   // micro row group
    const int arow = tid >> 2;   // 0..63  A-tile row this thread loads
    const int ac4  = tid & 3;    // which float4 of the 16-wide k slab
    const int wrow = tid >> 4;   // 0..15  W-tile row
    const int wc4  = tid & 15;   // which float4 of the 64-wide col slab

    float acc[4][4] = {};

    for (int k0 = 0; k0 < K; k0 += BK) {
        // load A tile (64 rows x 16 k), transpose into As
        {
            float4 av = make_float4(0.f, 0.f, 0.f, 0.f);
            int gr = row0 + arow;
            if (gr < N)
                av = *(const float4*)(A + (size_t)gr * K + k0 + ac4 * 4);
            As[ac4 * 4 + 0][arow] = av.x;
            As[ac4 * 4 + 1][arow] = av.y;
            As[ac4 * 4 + 2][arow] = av.z;
            As[ac4 * 4 + 3][arow] = av.w;
        }
        // load W tile (16 k x 64 cols)
        {
            float4 wv = make_float4(0.f, 0.f, 0.f, 0.f);
            int gc = col0 + wc4 * 4;
            if (gc + 3 < M)
                wv = *(const float4*)(W + (size_t)(k0 + wrow) * M + gc);
            *(float4*)&Bs[wrow][wc4 * 4] = wv;
        }
        __syncthreads();
#pragma unroll
        for (int k = 0; k < BK; ++k) {
            float4 a = *(const float4*)&As[k][ty * 4];
            float4 b = *(const float4*)&Bs[k][tx * 4];
            acc[0][0] += a.x * b.x; acc[0][1] += a.x * b.y; acc[0][2] += a.x * b.z; acc[0][3] += a.x * b.w;
            acc[1][0] += a.y * b.x; acc[1][1] += a.y * b.y; acc[1][2] += a.y * b.z; acc[1][3] += a.y * b.w;
            acc[2][0] += a.z * b.x; acc[2][1] += a.z * b.y; acc[2][2] += a.z * b.z; acc[2][3] += a.z * b.w;
            acc[3][0] += a.w * b.x; acc[3][1] += a.w * b.y; acc[3][2] += a.w * b.z; acc[3][3] += a.w * b.w;
        }
        __syncthreads();
    }

    const int gc0 = col0 + tx * 4;
    if (gc0 + 3 < M) {
#pragma unroll
        for (int m = 0; m < 4; ++m) {
            int gr = row0 + ty * 4 + m;
            if (gr < N) {
                float4 v = make_float4(acc[m][0], acc[m][1], acc[m][2], acc[m][3]);
                *(float4*)(C + (size_t)gr * M + gc0) = v;
            }
        }
    }
}

// -------------- edge scatter-add: out[dst] += ew * h[src] ------------------
// C4 = feats/4. For C4=64 one wave handles exactly one edge (s/d/w uniform).
template <int C4>
__global__ __launch_bounds__(256) void scatter_add(const float4* __restrict__ h4,
                                                   const int* __restrict__ src,
                                                   const int* __restrict__ dst,
                                                   const float* __restrict__ ew,
                                                   float* __restrict__ out,
                                                   long long total) {
    long long idx = (long long)blockIdx.x * blockDim.x + threadIdx.x;
    if (idx >= total) return;
    int e = (int)(idx / C4);
    int c = (int)(idx - (long long)e * C4);
    int s = src[e];
    int d = dst[e];
    float w = ew[e];
    float4 v = h4[(long long)s * C4 + c];
    float* o = out + ((long long)d * C4 + c) * 4;
    atomicAdd(o + 0, v.x * w);
    atomicAdd(o + 1, v.y * w);
    atomicAdd(o + 2, v.z * w);
    atomicAdd(o + 3, v.w * w);
}

// -------------------- bias + relu, in place, float4 ------------------------
template <int C4>
__global__ __launch_bounds__(256) void bias_relu(float4* __restrict__ h4,
                                                 const float4* __restrict__ b4,
                                                 long long total) {
    long long idx = (long long)blockIdx.x * blockDim.x + threadIdx.x;
    if (idx >= total) return;
    int c = (int)(idx % C4);
    float4 v = h4[idx];
    float4 b = b4[c];
    v.x = fmaxf(v.x + b.x, 0.f);
    v.y = fmaxf(v.y + b.y, 0.f);
    v.z = fmaxf(v.z + b.z, 0.f);
    v.w = fmaxf(v.w + b.w, 0.f);
    h4[idx] = v;
}

// ------------- log_softmax over rows of M (=40), one wave/row --------------
__global__ __launch_bounds__(256) void logsoftmax_rows(float* __restrict__ out,
                                                       const float* __restrict__ b,
                                                       int N, int M) {
    int wave = threadIdx.x >> 6;
    int lane = threadIdx.x & 63;
    int row  = blockIdx.x * 4 + wave;
    if (row >= N) return;
    float val = 0.f;
    float v   = -INFINITY;
    if (lane < M) {
        val = out[(size_t)row * M + lane] + b[lane];
        v   = val;
    }
#pragma unroll
    for (int off = 32; off; off >>= 1)
        v = fmaxf(v, __shfl_xor(v, off, 64));
    float ex = (lane < M) ? expf(val - v) : 0.f;
#pragma unroll
    for (int off = 32; off; off >>= 1)
        ex += __shfl_xor(ex, off, 64);
    float ls = logf(ex);
    if (lane < M) out[(size_t)row * M + lane] = val - v - ls;
}

// ---------------------------------------------------------------------------
extern "C" void kernel_launch(void* const* d_in, const int* in_sizes, int n_in,
                              void* d_out, int out_size, void* d_ws, size_t ws_size,
                              hipStream_t stream) {
    const float* x   = (const float*)d_in[0];
    const int*  eidx = (const int*)d_in[1];
    const float* ew  = (const float*)d_in[2];
    const float* W1  = (const float*)d_in[3];
    const float* b1  = (const float*)d_in[4];
    const float* W2  = (const float*)d_in[5];
    const float* b2  = (const float*)d_in[6];
    const float* W3  = (const float*)d_in[7];
    const float* b3  = (const float*)d_in[8];
    const int* src = eidx;
    const int* dst = eidx + N_EDGES;
    float* out = (float*)d_out;

    float* A    = (float*)d_ws;                       // N_NODES*HID (pre-agg h)
    float* B    = A + (size_t)N_NODES * HID;          // N_NODES*HID (aggregated)
    float* Cbuf = B + (size_t)N_NODES * HID;          // N_NODES*OUT_CH

    dim3 blk(256);
    dim3 gridHid((HID + BN - 1) / BN, (N_NODES + BM - 1) / BM);
    dim3 gridOut((OUT_CH + BN - 1) / BN, (N_NODES + BM - 1) / BM);

    const long long totHid  = (long long)N_NODES * (HID / 4);
    const long long totEH   = (long long)N_EDGES * (HID / 4);
    const long long totEO   = (long long)N_EDGES * (OUT_CH / 4);

    // ---- layer 1: h = x @ W1 ; agg = scatter(h) ; B = relu(agg + b1)
    sgemm<<<gridHid, blk, 0, stream>>>(x, W1, A, N_NODES, IN_CH, HID);
    hipMemsetAsync(B, 0, (size_t)N_NODES * HID * sizeof(float), stream);
    scatter_add<HID / 4><<<(int)((totEH + 255) / 256), blk, 0, stream>>>(
        (const float4*)A, src, dst, ew, B, totEH);
    bias_relu<HID / 4><<<(int)((totHid + 255) / 256), blk, 0, stream>>>(
        (float4*)B, (const float4*)b1, totHid);

    // ---- layer 2: h = B @ W2 ; agg ; relu + b2
    sgemm<<<gridHid, blk, 0, stream>>>(B, W2, A, N_NODES, HID, HID);
    hipMemsetAsync(B, 0, (size_t)N_NODES * HID * sizeof(float), stream);
    scatter_add<HID / 4><<<(int)((totEH + 255) / 256), blk, 0, stream>>>(
        (const float4*)A, src, dst, ew, B, totEH);
    bias_relu<HID / 4><<<(int)((totHid + 255) / 256), blk, 0, stream>>>(
        (float4*)B, (const float4*)b2, totHid);

    // ---- layer 3: h = B @ W3 ; agg into d_out ; + b3 ; log_softmax
    sgemm<<<gridOut, blk, 0, stream>>>(B, W3, Cbuf, N_NODES, HID, OUT_CH);
    hipMemsetAsync(out, 0, (size_t)N_NODES * OUT_CH * sizeof(float), stream);
    scatter_add<OUT_CH / 4><<<(int)((totEO + 255) / 256), blk, 0, stream>>>(
        (const float4*)Cbuf, src, dst, ew, out, totEO);
    logsoftmax_rows<<<(N_NODES + 3) / 4, blk, 0, stream>>>(out, b3, N_NODES, OUT_CH);
}

// Round 2
// 701.606 us; speedup vs baseline: 8.7455x; 8.7455x over previous
//
#include <hip/hip_runtime.h>
#include <math.h>

#define N_NODES 50000
#define N_EDGES 800000
#define IN_CH 128
#define HID 256
#define OUT_CH 40

// ---------------- tiled fp32 GEMM: C[N,M] = A[N,K] @ W[K,M] ----------------
// Optional fused epilogue: bias add + relu.
#define BM 64
#define BN 64
#define BK 16

__global__ __launch_bounds__(256) void sgemm(const float* __restrict__ A,
                                             const float* __restrict__ W,
                                             float* __restrict__ C,
                                             int N, int K, int M,
                                             const float* __restrict__ bias,
                                             int act) {
    __shared__ __align__(16) float As[BK][BM + 4];
    __shared__ __align__(16) float Bs[BK][BN + 4];
    const int tid  = threadIdx.x;
    const int row0 = blockIdx.y * BM;
    const int col0 = blockIdx.x * BN;
    const int tx   = tid & 15;
    const int ty   = tid >> 4;
    const int arow = tid >> 2;
    const int ac4  = tid & 3;
    const int wrow = tid >> 4;
    const int wc4  = tid & 15;

    float acc[4][4] = {};

    for (int k0 = 0; k0 < K; k0 += BK) {
        {
            float4 av = make_float4(0.f, 0.f, 0.f, 0.f);
            int gr = row0 + arow;
            if (gr < N)
                av = *(const float4*)(A + (size_t)gr * K + k0 + ac4 * 4);
            As[ac4 * 4 + 0][arow] = av.x;
            As[ac4 * 4 + 1][arow] = av.y;
            As[ac4 * 4 + 2][arow] = av.z;
            As[ac4 * 4 + 3][arow] = av.w;
        }
        {
            float4 wv = make_float4(0.f, 0.f, 0.f, 0.f);
            int gc = col0 + wc4 * 4;
            if (gc + 3 < M)
                wv = *(const float4*)(W + (size_t)(k0 + wrow) * M + gc);
            *(float4*)&Bs[wrow][wc4 * 4] = wv;
        }
        __syncthreads();
#pragma unroll
        for (int k = 0; k < BK; ++k) {
            float4 a = *(const float4*)&As[k][ty * 4];
            float4 b = *(const float4*)&Bs[k][tx * 4];
            acc[0][0] += a.x * b.x; acc[0][1] += a.x * b.y; acc[0][2] += a.x * b.z; acc[0][3] += a.x * b.w;
            acc[1][0] += a.y * b.x; acc[1][1] += a.y * b.y; acc[1][2] += a.y * b.z; acc[1][3] += a.y * b.w;
            acc[2][0] += a.z * b.x; acc[2][1] += a.z * b.y; acc[2][2] += a.z * b.z; acc[2][3] += a.z * b.w;
            acc[3][0] += a.w * b.x; acc[3][1] += a.w * b.y; acc[3][2] += a.w * b.z; acc[3][3] += a.w * b.w;
        }
        __syncthreads();
    }

    const int gc0 = col0 + tx * 4;
    if (gc0 + 3 < M) {
        float4 bv = make_float4(0.f, 0.f, 0.f, 0.f);
        if (bias) bv = *(const float4*)(bias + gc0);
#pragma unroll
        for (int m = 0; m < 4; ++m) {
            int gr = row0 + ty * 4 + m;
            if (gr < N) {
                float4 v = make_float4(acc[m][0] + bv.x, acc[m][1] + bv.y,
                                       acc[m][2] + bv.z, acc[m][3] + bv.w);
                if (act) {
                    v.x = fmaxf(v.x, 0.f); v.y = fmaxf(v.y, 0.f);
                    v.z = fmaxf(v.z, 0.f); v.w = fmaxf(v.w, 0.f);
                }
                *(float4*)(C + (size_t)gr * M + gc0) = v;
            }
        }
    }
}

// ------------------------- CSR build (by dst) ------------------------------
__global__ __launch_bounds__(256) void hist_kernel(const int* __restrict__ dst,
                                                   int* __restrict__ deg) {
    int e = blockIdx.x * 256 + threadIdx.x;
    if (e < N_EDGES) atomicAdd(&deg[dst[e]], 1);
}

// single-block in-place exclusive scan of rs[0..n-1]; rs[n] = total; cursor copy
__global__ __launch_bounds__(1024) void scan_kernel(int* __restrict__ rs,
                                                    int* __restrict__ cursor,
                                                    int n) {
    __shared__ int buf[1024];
    __shared__ int carry;
    const int tid = threadIdx.x;
    if (tid == 0) carry = 0;
    __syncthreads();
    for (int base = 0; base < n; base += 1024) {
        int i = base + tid;
        int v = (i < n) ? rs[i] : 0;
        buf[tid] = v;
        __syncthreads();
        for (int off = 1; off < 1024; off <<= 1) {
            int t = (tid >= off) ? buf[tid - off] : 0;
            __syncthreads();
            buf[tid] += t;
            __syncthreads();
        }
        int excl = buf[tid] - v + carry;
        if (i < n) { rs[i] = excl; cursor[i] = excl; }
        __syncthreads();
        if (tid == 0) carry += buf[1023];
        __syncthreads();
    }
    if (tid == 0) rs[n] = carry;
}

__global__ __launch_bounds__(256) void fill_kernel(const int* __restrict__ src,
                                                   const int* __restrict__ dst,
                                                   const float* __restrict__ ew,
                                                   int* __restrict__ cursor,
                                                   int* __restrict__ csr_src,
                                                   float* __restrict__ csr_w) {
    int e = blockIdx.x * 256 + threadIdx.x;
    if (e >= N_EDGES) return;
    int slot = atomicAdd(&cursor[dst[e]], 1);
    csr_src[slot] = src[e];
    csr_w[slot] = ew[e];
}

// ---------------- gather aggregation: out[n] = sum_e w_e * h[src_e] --------
// VPN float4s per row; VPN threads per node (VPN = 64 for 256 feats, 32 for 128).
template <int VPN>
__global__ __launch_bounds__(256) void gather_agg(const float4* __restrict__ h4,
                                                  const int* __restrict__ rs,
                                                  const int* __restrict__ csr_src,
                                                  const float* __restrict__ csr_w,
                                                  float4* __restrict__ out4,
                                                  const float4* __restrict__ bias4,
                                                  int act, int n) {
    const int nodes_per_blk = 256 / VPN;
    int node = blockIdx.x * nodes_per_blk + threadIdx.x / VPN;
    int c = threadIdx.x % VPN;
    if (node >= n) return;
    int beg = rs[node], end = rs[node + 1];
    float4 a0 = make_float4(0.f, 0.f, 0.f, 0.f);
    float4 a1 = make_float4(0.f, 0.f, 0.f, 0.f);
    int i = beg;
    for (; i + 1 < end; i += 2) {
        int s0 = csr_src[i];     float w0 = csr_w[i];
        int s1 = csr_src[i + 1]; float w1 = csr_w[i + 1];
        float4 v0 = h4[(size_t)s0 * VPN + c];
        float4 v1 = h4[(size_t)s1 * VPN + c];
        a0.x += v0.x * w0; a0.y += v0.y * w0; a0.z += v0.z * w0; a0.w += v0.w * w0;
        a1.x += v1.x * w1; a1.y += v1.y * w1; a1.z += v1.z * w1; a1.w += v1.w * w1;
    }
    if (i < end) {
        int s0 = csr_src[i]; float w0 = csr_w[i];
        float4 v0 = h4[(size_t)s0 * VPN + c];
        a0.x += v0.x * w0; a0.y += v0.y * w0; a0.z += v0.z * w0; a0.w += v0.w * w0;
    }
    float4 r = make_float4(a0.x + a1.x, a0.y + a1.y, a0.z + a1.z, a0.w + a1.w);
    if (bias4) {
        float4 b = bias4[c];
        r.x += b.x; r.y += b.y; r.z += b.z; r.w += b.w;
    }
    if (act) {
        r.x = fmaxf(r.x, 0.f); r.y = fmaxf(r.y, 0.f);
        r.z = fmaxf(r.z, 0.f); r.w = fmaxf(r.w, 0.f);
    }
    out4[(size_t)node * VPN + c] = r;
}

// ---- final: gather 40-wide rows + bias + log_softmax, one wave per node ----
__global__ __launch_bounds__(256) void gather_lsm(const float* __restrict__ h,
                                                  const int* __restrict__ rs,
                                                  const int* __restrict__ csr_src,
                                                  const float* __restrict__ csr_w,
                                                  const float* __restrict__ b,
                                                  float* __restrict__ out, int n) {
    int wave = threadIdx.x >> 6;
    int lane = threadIdx.x & 63;
    int node = blockIdx.x * 4 + wave;
    if (node >= n) return;
    int beg = rs[node], end = rs[node + 1];
    float acc = 0.f;
    if (lane < OUT_CH) {
        for (int i = beg; i < end; ++i) {
            int s = csr_src[i];
            acc += h[(size_t)s * OUT_CH + lane] * csr_w[i];
        }
    }
    float val = 0.f, v = -INFINITY;
    if (lane < OUT_CH) {
        val = acc + b[lane];
        v = val;
    }
#pragma unroll
    for (int off = 32; off; off >>= 1)
        v = fmaxf(v, __shfl_xor(v, off, 64));
    float ex = (lane < OUT_CH) ? expf(val - v) : 0.f;
#pragma unroll
    for (int off = 32; off; off >>= 1)
        ex += __shfl_xor(ex, off, 64);
    float ls = logf(ex);
    if (lane < OUT_CH) out[(size_t)node * OUT_CH + lane] = val - v - ls;
}

// ---------------------------------------------------------------------------
extern "C" void kernel_launch(void* const* d_in, const int* in_sizes, int n_in,
                              void* d_out, int out_size, void* d_ws, size_t ws_size,
                              hipStream_t stream) {
    const float* x   = (const float*)d_in[0];
    const int*  eidx = (const int*)d_in[1];
    const float* ew  = (const float*)d_in[2];
    const float* W1  = (const float*)d_in[3];
    const float* b1  = (const float*)d_in[4];
    const float* W2  = (const float*)d_in[5];
    const float* b2  = (const float*)d_in[6];
    const float* W3  = (const float*)d_in[7];
    const float* b3  = (const float*)d_in[8];
    const int* src = eidx;
    const int* dst = eidx + N_EDGES;
    float* out = (float*)d_out;

    float* bufA = (float*)d_ws;                          // 50000*256 floats
    float* bufB = bufA + (size_t)N_NODES * HID;          // 50000*256 floats
    int*   rs      = (int*)(bufB + (size_t)N_NODES * HID); // 50001 ints
    int*   cursor  = rs + N_NODES + 2;                   // 50000 ints
    int*   csr_src = cursor + N_NODES;                   // 800000 ints
    float* csr_w   = (float*)(csr_src + N_EDGES);        // 800000 floats

    dim3 blk(256);
    const int edge_blocks = (N_EDGES + 255) / 256;

    // ---- CSR build (every call: ws is re-poisoned by the harness)
    hipMemsetAsync(rs, 0, (N_NODES + 1) * sizeof(int), stream);
    hist_kernel<<<edge_blocks, blk, 0, stream>>>(dst, rs);
    scan_kernel<<<1, 1024, 0, stream>>>(rs, cursor, N_NODES);
    fill_kernel<<<edge_blocks, blk, 0, stream>>>(src, dst, ew, cursor, csr_src, csr_w);

    // ---- layer 1 (swapped): AggX = gather(x); H1 = relu(AggX@W1 + b1)
    gather_agg<IN_CH / 4><<<(N_NODES * (IN_CH / 4) + 255) / 256, blk, 0, stream>>>(
        (const float4*)x, rs, csr_src, csr_w, (float4*)bufA, nullptr, 0, N_NODES);
    dim3 gridHid((HID + BN - 1) / BN, (N_NODES + BM - 1) / BM);
    sgemm<<<gridHid, blk, 0, stream>>>(bufA, W1, bufB, N_NODES, IN_CH, HID, b1, 1);

    // ---- layer 2: h = H1@W2 ; H2 = relu(gather(h) + b2)
    sgemm<<<gridHid, blk, 0, stream>>>(bufB, W2, bufA, N_NODES, HID, HID, nullptr, 0);
    gather_agg<HID / 4><<<(N_NODES * (HID / 4) + 255) / 256, blk, 0, stream>>>(
        (const float4*)bufA, rs, csr_src, csr_w, (float4*)bufB, (const float4*)b2, 1, N_NODES);

    // ---- layer 3: h = H2@W3 ; out = log_softmax(gather(h) + b3)
    dim3 gridOut((OUT_CH + BN - 1) / BN, (N_NODES + BM - 1) / BM);
    sgemm<<<gridOut, blk, 0, stream>>>(bufB, W3, bufA, N_NODES, HID, OUT_CH, nullptr, 0);
    gather_lsm<<<(N_NODES + 3) / 4, blk, 0, stream>>>(bufA, rs, csr_src, csr_w, b3, out, N_NODES);
}

// Round 3
// 528.125 us; speedup vs baseline: 11.6182x; 1.3285x over previous
//
#include <hip/hip_runtime.h>
#include <math.h>

#define N_NODES 50000
#define N_EDGES 800000
#define IN_CH 128
#define HID 256
#define OUT_CH 40

typedef __attribute__((ext_vector_type(8))) short short8;
typedef __attribute__((ext_vector_type(4))) float floatx4;

__device__ __forceinline__ unsigned short f2bf(float f) {
    unsigned int u = __float_as_uint(f);
    u += 0x7fff + ((u >> 16) & 1);
    return (unsigned short)(u >> 16);
}
__device__ __forceinline__ float bf2f(unsigned short h) {
    return __uint_as_float(((unsigned int)h) << 16);
}

// ------------------------- CSR build (by dst) ------------------------------
__global__ __launch_bounds__(256) void hist_kernel(const int* __restrict__ dst,
                                                   int* __restrict__ deg) {
    int e = blockIdx.x * 256 + threadIdx.x;
    if (e < N_EDGES) atomicAdd(&deg[dst[e]], 1);
}

__global__ __launch_bounds__(1024) void scan_kernel(int* __restrict__ rs,
                                                    int* __restrict__ cursor,
                                                    int n) {
    __shared__ int buf[1024];
    __shared__ int carry;
    const int tid = threadIdx.x;
    if (tid == 0) carry = 0;
    __syncthreads();
    for (int base = 0; base < n; base += 1024) {
        int i = base + tid;
        int v = (i < n) ? rs[i] : 0;
        buf[tid] = v;
        __syncthreads();
        for (int off = 1; off < 1024; off <<= 1) {
            int t = (tid >= off) ? buf[tid - off] : 0;
            __syncthreads();
            buf[tid] += t;
            __syncthreads();
        }
        int excl = buf[tid] - v + carry;
        if (i < n) { rs[i] = excl; cursor[i] = excl; }
        __syncthreads();
        if (tid == 0) carry += buf[1023];
        __syncthreads();
    }
    if (tid == 0) rs[n] = carry;
}

__global__ __launch_bounds__(256) void fill_kernel(const int* __restrict__ src,
                                                   const int* __restrict__ dst,
                                                   const float* __restrict__ ew,
                                                   int* __restrict__ cursor,
                                                   int* __restrict__ csr_src,
                                                   float* __restrict__ csr_w) {
    int e = blockIdx.x * 256 + threadIdx.x;
    if (e >= N_EDGES) return;
    int slot = atomicAdd(&cursor[dst[e]], 1);
    csr_src[slot] = src[e];
    csr_w[slot] = ew[e];
}

// ------------- weight cast + transpose: Wt[m][k] = bf16(W[k][m]) -----------
__global__ __launch_bounds__(256) void wt_bf16_t(const float* __restrict__ W,
                                                 short* __restrict__ Wt,
                                                 int K, int M) {
    int idx = blockIdx.x * 256 + threadIdx.x;
    if (idx >= K * M) return;
    int m = idx / K, k = idx - m * K;
    Wt[idx] = (short)f2bf(W[(size_t)k * M + m]);
}

// -------- gather layer1: agg(x) fp32 -> bf16 out, 32 thr/node x 4 feats ----
__global__ __launch_bounds__(256) void gather_x_bf16(const float4* __restrict__ x4,
                                                     const int* __restrict__ rs,
                                                     const int* __restrict__ csr_src,
                                                     const float* __restrict__ csr_w,
                                                     unsigned short* __restrict__ out) {
    int node = blockIdx.x * 8 + (threadIdx.x >> 5);
    int c = threadIdx.x & 31;
    if (node >= N_NODES) return;
    int beg = rs[node], end = rs[node + 1];
    float a0 = 0.f, a1 = 0.f, a2 = 0.f, a3 = 0.f;
    for (int i = beg; i < end; ++i) {
        int s = csr_src[i];
        float w = csr_w[i];
        float4 v = x4[(size_t)s * 32 + c];
        a0 += v.x * w; a1 += v.y * w; a2 += v.z * w; a3 += v.w * w;
    }
    ushort4 o = make_ushort4(f2bf(a0), f2bf(a1), f2bf(a2), f2bf(a3));
    *(ushort4*)(out + (size_t)node * 128 + c * 4) = o;
}

// ---- gather layer2: agg(h) bf16 -> bias+relu -> bf16, 32 thr/node x 8 -----
__global__ __launch_bounds__(256) void gather_h_bf16(const unsigned short* __restrict__ h,
                                                     const int* __restrict__ rs,
                                                     const int* __restrict__ csr_src,
                                                     const float* __restrict__ csr_w,
                                                     const float* __restrict__ bias,
                                                     unsigned short* __restrict__ out) {
    int node = blockIdx.x * 8 + (threadIdx.x >> 5);
    int c = threadIdx.x & 31;
    if (node >= N_NODES) return;
    int beg = rs[node], end = rs[node + 1];
    float acc[8] = {};
    for (int i = beg; i < end; ++i) {
        int s = csr_src[i];
        float w = csr_w[i];
        short8 v = *(const short8*)(h + (size_t)s * 256 + c * 8);
#pragma unroll
        for (int j = 0; j < 8; ++j)
            acc[j] += bf2f((unsigned short)v[j]) * w;
    }
    short8 ov;
#pragma unroll
    for (int j = 0; j < 8; ++j) {
        float r = fmaxf(acc[j] + bias[c * 8 + j], 0.f);
        ov[j] = (short)f2bf(r);
    }
    *(short8*)(out + (size_t)node * 256 + c * 8) = ov;
}

// --------------- bf16 MFMA GEMM: C[N,M] = A[N,K] @ Wt[M,K]^T ---------------
// BM=128, BN=64, BK=32; 256 threads = 4 waves (2x2); 16x16x32 bf16 MFMA.
// LDS chunk-XOR swizzle keeps ds_read_b128 at the free 2-way conflict level.
template <int OUT_BF16>
__global__ __launch_bounds__(256) void mfma_gemm(const short* __restrict__ A,
                                                 const short* __restrict__ Wt,
                                                 void* __restrict__ Cout,
                                                 int N, int K, int M,
                                                 const float* __restrict__ bias,
                                                 int act) {
    __shared__ short As[128 * 32];
    __shared__ short Bs[64 * 32];
    const int tid = threadIdx.x;
    const int lane = tid & 63;
    const int wave = tid >> 6;
    const int wr = wave >> 1, wc = wave & 1;
    const int row0 = blockIdx.y * 128;
    const int col0 = blockIdx.x * 64;

    floatx4 acc[4][2];
#pragma unroll
    for (int t = 0; t < 4; ++t)
#pragma unroll
        for (int u = 0; u < 2; ++u) acc[t][u] = (floatx4){0.f, 0.f, 0.f, 0.f};

    for (int k0 = 0; k0 < K; k0 += 32) {
        // stage A tile: 128 rows x 32 k, 2x 16B chunks per thread
#pragma unroll
        for (int i = 0; i < 2; ++i) {
            int idx = tid + i * 256;
            int r = idx >> 2, ch = idx & 3;
            int gr = row0 + r;
            int4 v = make_int4(0, 0, 0, 0);
            if (gr < N) v = *(const int4*)(A + (size_t)gr * K + k0 + ch * 8);
            *(int4*)&As[r * 32 + ((ch ^ ((r >> 1) & 3)) << 3)] = v;
        }
        // stage B tile: 64 n-rows x 32 k, 1 chunk per thread
        {
            int r = tid >> 2, ch = tid & 3;
            int gn = col0 + r;
            int4 v = make_int4(0, 0, 0, 0);
            if (gn < M) v = *(const int4*)(Wt + (size_t)gn * K + k0 + ch * 8);
            *(int4*)&Bs[r * 32 + ((ch ^ ((r >> 1) & 3)) << 3)] = v;
        }
        __syncthreads();

        short8 bf[2];
#pragma unroll
        for (int u = 0; u < 2; ++u) {
            int n = wc * 32 + u * 16 + (lane & 15);
            int ch = (lane >> 4) ^ ((n >> 1) & 3);
            bf[u] = *(const short8*)&Bs[n * 32 + (ch << 3)];
        }
#pragma unroll
        for (int t = 0; t < 4; ++t) {
            int r = wr * 64 + t * 16 + (lane & 15);
            int ch = (lane >> 4) ^ ((r >> 1) & 3);
            short8 af = *(const short8*)&As[r * 32 + (ch << 3)];
            acc[t][0] = __builtin_amdgcn_mfma_f32_16x16x32_bf16(af, bf[0], acc[t][0], 0, 0, 0);
            acc[t][1] = __builtin_amdgcn_mfma_f32_16x16x32_bf16(af, bf[1], acc[t][1], 0, 0, 0);
        }
        __syncthreads();
    }

    // epilogue: C/D layout col=lane&15, row=(lane>>4)*4+reg
#pragma unroll
    for (int t = 0; t < 4; ++t) {
#pragma unroll
        for (int u = 0; u < 2; ++u) {
            int gcol = col0 + wc * 32 + u * 16 + (lane & 15);
            if (gcol >= M) continue;
            float bv = bias ? bias[gcol] : 0.f;
#pragma unroll
            for (int reg = 0; reg < 4; ++reg) {
                int grow = row0 + wr * 64 + t * 16 + (lane >> 4) * 4 + reg;
                if (grow >= N) continue;
                float v = acc[t][u][reg] + bv;
                if (act) v = fmaxf(v, 0.f);
                if (OUT_BF16)
                    ((unsigned short*)Cout)[(size_t)grow * M + gcol] = f2bf(v);
                else
                    ((float*)Cout)[(size_t)grow * M + gcol] = v;
            }
        }
    }
}

// ---- final: gather 40-wide rows + bias + log_softmax, one wave per node ---
__global__ __launch_bounds__(256) void gather_lsm(const float* __restrict__ h,
                                                  const int* __restrict__ rs,
                                                  const int* __restrict__ csr_src,
                                                  const float* __restrict__ csr_w,
                                                  const float* __restrict__ b,
                                                  float* __restrict__ out, int n) {
    int wave = threadIdx.x >> 6;
    int lane = threadIdx.x & 63;
    int node = blockIdx.x * 4 + wave;
    if (node >= n) return;
    int beg = rs[node], end = rs[node + 1];
    float acc = 0.f;
    if (lane < OUT_CH) {
        for (int i = beg; i < end; ++i) {
            int s = csr_src[i];
            acc += h[(size_t)s * OUT_CH + lane] * csr_w[i];
        }
    }
    float val = 0.f, v = -INFINITY;
    if (lane < OUT_CH) {
        val = acc + b[lane];
        v = val;
    }
#pragma unroll
    for (int off = 32; off; off >>= 1)
        v = fmaxf(v, __shfl_xor(v, off, 64));
    float ex = (lane < OUT_CH) ? expf(val - v) : 0.f;
#pragma unroll
    for (int off = 32; off; off >>= 1)
        ex += __shfl_xor(ex, off, 64);
    float ls = logf(ex);
    if (lane < OUT_CH) out[(size_t)node * OUT_CH + lane] = val - v - ls;
}

// ---------------------------------------------------------------------------
extern "C" void kernel_launch(void* const* d_in, const int* in_sizes, int n_in,
                              void* d_out, int out_size, void* d_ws, size_t ws_size,
                              hipStream_t stream) {
    const float* x   = (const float*)d_in[0];
    const int*  eidx = (const int*)d_in[1];
    const float* ew  = (const float*)d_in[2];
    const float* W1  = (const float*)d_in[3];
    const float* b1  = (const float*)d_in[4];
    const float* W2  = (const float*)d_in[5];
    const float* b2  = (const float*)d_in[6];
    const float* W3  = (const float*)d_in[7];
    const float* b3  = (const float*)d_in[8];
    const int* src = eidx;
    const int* dst = eidx + N_EDGES;
    float* out = (float*)d_out;

    // ---- workspace layout (bf16 activations) ----
    short* aggX = (short*)d_ws;                             // 50000*128 bf16
    short* H1   = aggX + (size_t)N_NODES * IN_CH;           // 50000*256 bf16
    short* h2p  = H1   + (size_t)N_NODES * HID;             // 50000*256 bf16
    short* H2   = h2p  + (size_t)N_NODES * HID;             // 50000*256 bf16
    float* h3p  = (float*)(H2 + (size_t)N_NODES * HID);     // 50000*40 fp32
    short* Wt1  = (short*)(h3p + (size_t)N_NODES * OUT_CH); // 256*128 bf16
    short* Wt2  = Wt1 + HID * IN_CH;                        // 256*256 bf16
    short* Wt3  = Wt2 + HID * HID;                          // 40*256 bf16
    int*   rs      = (int*)(Wt3 + OUT_CH * HID);            // 50001(+pad)
    int*   cursor  = rs + N_NODES + 2;
    int*   csr_src = cursor + N_NODES;
    float* csr_w   = (float*)(csr_src + N_EDGES);

    dim3 blk(256);
    const int edge_blocks = (N_EDGES + 255) / 256;

    // ---- CSR build
    hipMemsetAsync(rs, 0, (N_NODES + 1) * sizeof(int), stream);
    hist_kernel<<<edge_blocks, blk, 0, stream>>>(dst, rs);
    scan_kernel<<<1, 1024, 0, stream>>>(rs, cursor, N_NODES);
    fill_kernel<<<edge_blocks, blk, 0, stream>>>(src, dst, ew, cursor, csr_src, csr_w);

    // ---- weight casts (tiny)
    wt_bf16_t<<<(IN_CH * HID + 255) / 256, blk, 0, stream>>>(W1, Wt1, IN_CH, HID);
    wt_bf16_t<<<(HID * HID + 255) / 256, blk, 0, stream>>>(W2, Wt2, HID, HID);
    wt_bf16_t<<<(HID * OUT_CH + 255) / 256, blk, 0, stream>>>(W3, Wt3, HID, OUT_CH);

    // ---- layer 1 (swapped): aggX = gather(x); H1 = relu(aggX@W1 + b1)
    gather_x_bf16<<<(N_NODES + 7) / 8, blk, 0, stream>>>(
        (const float4*)x, rs, csr_src, csr_w, (unsigned short*)aggX);
    {
        dim3 grid((HID + 63) / 64, (N_NODES + 127) / 128);
        mfma_gemm<1><<<grid, blk, 0, stream>>>(aggX, Wt1, H1, N_NODES, IN_CH, HID, b1, 1);
    }

    // ---- layer 2: h2p = H1@W2 ; H2 = relu(gather(h2p) + b2)
    {
        dim3 grid((HID + 63) / 64, (N_NODES + 127) / 128);
        mfma_gemm<1><<<grid, blk, 0, stream>>>(H1, Wt2, h2p, N_NODES, HID, HID, nullptr, 0);
    }
    gather_h_bf16<<<(N_NODES + 7) / 8, blk, 0, stream>>>(
        (const unsigned short*)h2p, rs, csr_src, csr_w, b2, (unsigned short*)H2);

    // ---- layer 3: h3p = H2@W3 ; out = log_softmax(gather(h3p) + b3)
    {
        dim3 grid((OUT_CH + 63) / 64, (N_NODES + 127) / 128);
        mfma_gemm<0><<<grid, blk, 0, stream>>>(H2, Wt3, h3p, N_NODES, HID, OUT_CH, nullptr, 0);
    }
    gather_lsm<<<(N_NODES + 3) / 4, blk, 0, stream>>>(h3p, rs, csr_src, csr_w, b3, out, N_NODES);
}

// Round 4
// 455.671 us; speedup vs baseline: 13.4656x; 1.1590x over previous
//
#include <hip/hip_runtime.h>
#include <math.h>

#define N_NODES 50000
#define N_EDGES 800000
#define IN_CH 128
#define HID 256
#define OUT_CH 40

typedef __attribute__((ext_vector_type(8))) short short8;
typedef __attribute__((ext_vector_type(4))) float floatx4;

__device__ __forceinline__ unsigned short f2bf(float f) {
    unsigned int u = __float_as_uint(f);
    u += 0x7fff + ((u >> 16) & 1);
    return (unsigned short)(u >> 16);
}
__device__ __forceinline__ float bf2f(unsigned short h) {
    return __uint_as_float(((unsigned int)h) << 16);
}

// ------------------------- CSR build (by dst) ------------------------------
__global__ __launch_bounds__(256) void hist_kernel(const int* __restrict__ dst,
                                                   int* __restrict__ deg) {
    int e = blockIdx.x * 256 + threadIdx.x;
    if (e < N_EDGES) atomicAdd(&deg[dst[e]], 1);
}

// ---- hierarchical exclusive scan over rs[0..n-1] ----
// phase 1: per-block (256 elems) exclusive scan in place + block totals
__global__ __launch_bounds__(256) void scan_blocks(int* __restrict__ rs,
                                                   int* __restrict__ partials,
                                                   int n) {
    __shared__ int wsum[4];
    int i = blockIdx.x * 256 + threadIdx.x;
    int lane = threadIdx.x & 63;
    int wave = threadIdx.x >> 6;
    int orig = (i < n) ? rs[i] : 0;
    int v = orig;
#pragma unroll
    for (int off = 1; off < 64; off <<= 1) {
        int t = __shfl_up(v, off, 64);
        if (lane >= off) v += t;
    }
    if (lane == 63) wsum[wave] = v;
    __syncthreads();
    int woff = 0;
#pragma unroll
    for (int w = 0; w < 4; ++w)
        if (w < wave) woff += wsum[w];
    int excl = woff + v - orig;
    if (i < n) rs[i] = excl;
    if (threadIdx.x == 255) partials[blockIdx.x] = woff + v;
}

// phase 2: single block scans the block totals (nb <= 256), writes rs[n]=total
__global__ __launch_bounds__(256) void scan_partials(int* __restrict__ partials,
                                                     int* __restrict__ rs,
                                                     int nb, int n) {
    __shared__ int wsum[4];
    int lane = threadIdx.x & 63;
    int wave = threadIdx.x >> 6;
    int orig = (threadIdx.x < nb) ? partials[threadIdx.x] : 0;
    int v = orig;
#pragma unroll
    for (int off = 1; off < 64; off <<= 1) {
        int t = __shfl_up(v, off, 64);
        if (lane >= off) v += t;
    }
    if (lane == 63) wsum[wave] = v;
    __syncthreads();
    int woff = 0;
#pragma unroll
    for (int w = 0; w < 4; ++w)
        if (w < wave) woff += wsum[w];
    int excl = woff + v - orig;
    if (threadIdx.x < nb) partials[threadIdx.x] = excl;
    if (threadIdx.x == 255) rs[n] = woff + v;
}

// phase 3: add block offsets, mirror into cursor
__global__ __launch_bounds__(256) void scan_add(int* __restrict__ rs,
                                                const int* __restrict__ partials,
                                                int* __restrict__ cursor, int n) {
    int i = blockIdx.x * 256 + threadIdx.x;
    if (i >= n) return;
    int v = rs[i] + partials[blockIdx.x];
    rs[i] = v;
    cursor[i] = v;
}

__global__ __launch_bounds__(256) void fill_kernel(const int* __restrict__ src,
                                                   const int* __restrict__ dst,
                                                   const float* __restrict__ ew,
                                                   int* __restrict__ cursor,
                                                   int* __restrict__ csr_src,
                                                   float* __restrict__ csr_w) {
    int e = blockIdx.x * 256 + threadIdx.x;
    if (e >= N_EDGES) return;
    int slot = atomicAdd(&cursor[dst[e]], 1);
    csr_src[slot] = src[e];
    csr_w[slot] = ew[e];
}

// ------------- weight cast + transpose: Wt[m][k] = bf16(W[k][m]) -----------
__global__ __launch_bounds__(256) void wt_bf16_t(const float* __restrict__ W,
                                                 short* __restrict__ Wt,
                                                 int K, int M) {
    int idx = blockIdx.x * 256 + threadIdx.x;
    if (idx >= K * M) return;
    int m = idx / K, k = idx - m * K;
    Wt[idx] = (short)f2bf(W[(size_t)k * M + m]);
}

// -------- gather layer1: agg(x) fp32 -> bf16 out, 32 thr/node x 4 feats ----
__global__ __launch_bounds__(256) void gather_x_bf16(const float4* __restrict__ x4,
                                                     const int* __restrict__ rs,
                                                     const int* __restrict__ csr_src,
                                                     const float* __restrict__ csr_w,
                                                     unsigned short* __restrict__ out) {
    int node = blockIdx.x * 8 + (threadIdx.x >> 5);
    int c = threadIdx.x & 31;
    if (node >= N_NODES) return;
    int beg = rs[node], end = rs[node + 1];
    float a0 = 0.f, a1 = 0.f, a2 = 0.f, a3 = 0.f;
    for (int i = beg; i < end; ++i) {
        int s = csr_src[i];
        float w = csr_w[i];
        float4 v = x4[(size_t)s * 32 + c];
        a0 += v.x * w; a1 += v.y * w; a2 += v.z * w; a3 += v.w * w;
    }
    ushort4 o = make_ushort4(f2bf(a0), f2bf(a1), f2bf(a2), f2bf(a3));
    *(ushort4*)(out + (size_t)node * 128 + c * 4) = o;
}

// ---- gather layer2: agg(h) bf16 -> bias+relu -> bf16, 32 thr/node x 8 -----
__global__ __launch_bounds__(256) void gather_h_bf16(const unsigned short* __restrict__ h,
                                                     const int* __restrict__ rs,
                                                     const int* __restrict__ csr_src,
                                                     const float* __restrict__ csr_w,
                                                     const float* __restrict__ bias,
                                                     unsigned short* __restrict__ out) {
    int node = blockIdx.x * 8 + (threadIdx.x >> 5);
    int c = threadIdx.x & 31;
    if (node >= N_NODES) return;
    int beg = rs[node], end = rs[node + 1];
    float acc[8] = {};
    for (int i = beg; i < end; ++i) {
        int s = csr_src[i];
        float w = csr_w[i];
        short8 v = *(const short8*)(h + (size_t)s * 256 + c * 8);
#pragma unroll
        for (int j = 0; j < 8; ++j)
            acc[j] += bf2f((unsigned short)v[j]) * w;
    }
    short8 ov;
#pragma unroll
    for (int j = 0; j < 8; ++j) {
        float r = fmaxf(acc[j] + bias[c * 8 + j], 0.f);
        ov[j] = (short)f2bf(r);
    }
    *(short8*)(out + (size_t)node * 256 + c * 8) = ov;
}

// --------------- bf16 MFMA GEMM: C[N,M] = A[N,K] @ Wt[M,K]^T ---------------
// BM=128, BN=64, BK=32; 256 threads = 4 waves (2x2); 16x16x32 bf16 MFMA.
template <int OUT_BF16>
__global__ __launch_bounds__(256) void mfma_gemm(const short* __restrict__ A,
                                                 const short* __restrict__ Wt,
                                                 void* __restrict__ Cout,
                                                 int N, int K, int M,
                                                 const float* __restrict__ bias,
                                                 int act) {
    __shared__ short As[128 * 32];
    __shared__ short Bs[64 * 32];
    const int tid = threadIdx.x;
    const int lane = tid & 63;
    const int wave = tid >> 6;
    const int wr = wave >> 1, wc = wave & 1;
    const int row0 = blockIdx.y * 128;
    const int col0 = blockIdx.x * 64;

    floatx4 acc[4][2];
#pragma unroll
    for (int t = 0; t < 4; ++t)
#pragma unroll
        for (int u = 0; u < 2; ++u) acc[t][u] = (floatx4){0.f, 0.f, 0.f, 0.f};

    for (int k0 = 0; k0 < K; k0 += 32) {
#pragma unroll
        for (int i = 0; i < 2; ++i) {
            int idx = tid + i * 256;
            int r = idx >> 2, ch = idx & 3;
            int gr = row0 + r;
            int4 v = make_int4(0, 0, 0, 0);
            if (gr < N) v = *(const int4*)(A + (size_t)gr * K + k0 + ch * 8);
            *(int4*)&As[r * 32 + ((ch ^ ((r >> 1) & 3)) << 3)] = v;
        }
        {
            int r = tid >> 2, ch = tid & 3;
            int gn = col0 + r;
            int4 v = make_int4(0, 0, 0, 0);
            if (gn < M) v = *(const int4*)(Wt + (size_t)gn * K + k0 + ch * 8);
            *(int4*)&Bs[r * 32 + ((ch ^ ((r >> 1) & 3)) << 3)] = v;
        }
        __syncthreads();

        short8 bf[2];
#pragma unroll
        for (int u = 0; u < 2; ++u) {
            int n = wc * 32 + u * 16 + (lane & 15);
            int ch = (lane >> 4) ^ ((n >> 1) & 3);
            bf[u] = *(const short8*)&Bs[n * 32 + (ch << 3)];
        }
#pragma unroll
        for (int t = 0; t < 4; ++t) {
            int r = wr * 64 + t * 16 + (lane & 15);
            int ch = (lane >> 4) ^ ((r >> 1) & 3);
            short8 af = *(const short8*)&As[r * 32 + (ch << 3)];
            acc[t][0] = __builtin_amdgcn_mfma_f32_16x16x32_bf16(af, bf[0], acc[t][0], 0, 0, 0);
            acc[t][1] = __builtin_amdgcn_mfma_f32_16x16x32_bf16(af, bf[1], acc[t][1], 0, 0, 0);
        }
        __syncthreads();
    }

#pragma unroll
    for (int t = 0; t < 4; ++t) {
#pragma unroll
        for (int u = 0; u < 2; ++u) {
            int gcol = col0 + wc * 32 + u * 16 + (lane & 15);
            if (gcol >= M) continue;
            float bv = bias ? bias[gcol] : 0.f;
#pragma unroll
            for (int reg = 0; reg < 4; ++reg) {
                int grow = row0 + wr * 64 + t * 16 + (lane >> 4) * 4 + reg;
                if (grow >= N) continue;
                float v = acc[t][u][reg] + bv;
                if (act) v = fmaxf(v, 0.f);
                if (OUT_BF16)
                    ((unsigned short*)Cout)[(size_t)grow * M + gcol] = f2bf(v);
                else
                    ((float*)Cout)[(size_t)grow * M + gcol] = v;
            }
        }
    }
}

// ---- final: gather 40-wide rows + bias + log_softmax, one wave per node ---
__global__ __launch_bounds__(256) void gather_lsm(const float* __restrict__ h,
                                                  const int* __restrict__ rs,
                                                  const int* __restrict__ csr_src,
                                                  const float* __restrict__ csr_w,
                                                  const float* __restrict__ b,
                                                  float* __restrict__ out, int n) {
    int wave = threadIdx.x >> 6;
    int lane = threadIdx.x & 63;
    int node = blockIdx.x * 4 + wave;
    if (node >= n) return;
    int beg = rs[node], end = rs[node + 1];
    float acc = 0.f;
    if (lane < OUT_CH) {
        for (int i = beg; i < end; ++i) {
            int s = csr_src[i];
            acc += h[(size_t)s * OUT_CH + lane] * csr_w[i];
        }
    }
    float val = 0.f, v = -INFINITY;
    if (lane < OUT_CH) {
        val = acc + b[lane];
        v = val;
    }
#pragma unroll
    for (int off = 32; off; off >>= 1)
        v = fmaxf(v, __shfl_xor(v, off, 64));
    float ex = (lane < OUT_CH) ? expf(val - v) : 0.f;
#pragma unroll
    for (int off = 32; off; off >>= 1)
        ex += __shfl_xor(ex, off, 64);
    float ls = logf(ex);
    if (lane < OUT_CH) out[(size_t)node * OUT_CH + lane] = val - v - ls;
}

// ---------------------------------------------------------------------------
extern "C" void kernel_launch(void* const* d_in, const int* in_sizes, int n_in,
                              void* d_out, int out_size, void* d_ws, size_t ws_size,
                              hipStream_t stream) {
    const float* x   = (const float*)d_in[0];
    const int*  eidx = (const int*)d_in[1];
    const float* ew  = (const float*)d_in[2];
    const float* W1  = (const float*)d_in[3];
    const float* b1  = (const float*)d_in[4];
    const float* W2  = (const float*)d_in[5];
    const float* b2  = (const float*)d_in[6];
    const float* W3  = (const float*)d_in[7];
    const float* b3  = (const float*)d_in[8];
    const int* src = eidx;
    const int* dst = eidx + N_EDGES;
    float* out = (float*)d_out;

    // ---- workspace layout (bf16 activations) ----
    short* aggX = (short*)d_ws;                             // 50000*128 bf16
    short* H1   = aggX + (size_t)N_NODES * IN_CH;           // 50000*256 bf16
    short* h2p  = H1   + (size_t)N_NODES * HID;             // 50000*256 bf16
    short* H2   = h2p  + (size_t)N_NODES * HID;             // 50000*256 bf16
    float* h3p  = (float*)(H2 + (size_t)N_NODES * HID);     // 50000*40 fp32
    short* Wt1  = (short*)(h3p + (size_t)N_NODES * OUT_CH); // 256*128 bf16
    short* Wt2  = Wt1 + HID * IN_CH;                        // 256*256 bf16
    short* Wt3  = Wt2 + HID * HID;                          // 40*256 bf16
    int*   rs      = (int*)(Wt3 + OUT_CH * HID);            // 50001(+pad)
    int*   cursor  = rs + N_NODES + 2;
    int*   csr_src = cursor + N_NODES;
    float* csr_w   = (float*)(csr_src + N_EDGES);
    int*   partials = (int*)(csr_w + N_EDGES);              // <=256 ints

    dim3 blk(256);
    const int edge_blocks = (N_EDGES + 255) / 256;
    const int node_blocks = (N_NODES + 255) / 256;

    // ---- CSR build
    hipMemsetAsync(rs, 0, (N_NODES + 1) * sizeof(int), stream);
    hist_kernel<<<edge_blocks, blk, 0, stream>>>(dst, rs);
    scan_blocks<<<node_blocks, blk, 0, stream>>>(rs, partials, N_NODES);
    scan_partials<<<1, blk, 0, stream>>>(partials, rs, node_blocks, N_NODES);
    scan_add<<<node_blocks, blk, 0, stream>>>(rs, partials, cursor, N_NODES);
    fill_kernel<<<edge_blocks, blk, 0, stream>>>(src, dst, ew, cursor, csr_src, csr_w);

    // ---- weight casts (tiny)
    wt_bf16_t<<<(IN_CH * HID + 255) / 256, blk, 0, stream>>>(W1, Wt1, IN_CH, HID);
    wt_bf16_t<<<(HID * HID + 255) / 256, blk, 0, stream>>>(W2, Wt2, HID, HID);
    wt_bf16_t<<<(HID * OUT_CH + 255) / 256, blk, 0, stream>>>(W3, Wt3, HID, OUT_CH);

    // ---- layer 1 (swapped): aggX = gather(x); H1 = relu(aggX@W1 + b1)
    gather_x_bf16<<<(N_NODES + 7) / 8, blk, 0, stream>>>(
        (const float4*)x, rs, csr_src, csr_w, (unsigned short*)aggX);
    {
        dim3 grid((HID + 63) / 64, (N_NODES + 127) / 128);
        mfma_gemm<1><<<grid, blk, 0, stream>>>(aggX, Wt1, H1, N_NODES, IN_CH, HID, b1, 1);
    }

    // ---- layer 2: h2p = H1@W2 ; H2 = relu(gather(h2p) + b2)
    {
        dim3 grid((HID + 63) / 64, (N_NODES + 127) / 128);
        mfma_gemm<1><<<grid, blk, 0, stream>>>(H1, Wt2, h2p, N_NODES, HID, HID, nullptr, 0);
    }
    gather_h_bf16<<<(N_NODES + 7) / 8, blk, 0, stream>>>(
        (const unsigned short*)h2p, rs, csr_src, csr_w, b2, (unsigned short*)H2);

    // ---- layer 3: h3p = H2@W3 ; out = log_softmax(gather(h3p) + b3)
    {
        dim3 grid((OUT_CH + 63) / 64, (N_NODES + 127) / 128);
        mfma_gemm<0><<<grid, blk, 0, stream>>>(H2, Wt3, h3p, N_NODES, HID, OUT_CH, nullptr, 0);
    }
    gather_lsm<<<(N_NODES + 3) / 4, blk, 0, stream>>>(h3p, rs, csr_src, csr_w, b3, out, N_NODES);
}

// Round 5
// 392.498 us; speedup vs baseline: 15.6329x; 1.1610x over previous
//
#include <hip/hip_runtime.h>
#include <math.h>

#define N_NODES 50000
#define N_EDGES 800000
#define IN_CH 128
#define HID 256
#define OUT_CH 40

typedef __attribute__((ext_vector_type(8))) short short8;
typedef __attribute__((ext_vector_type(4))) float floatx4;

__device__ __forceinline__ unsigned short f2bf(float f) {
    unsigned int u = __float_as_uint(f);
    u += 0x7fff + ((u >> 16) & 1);
    return (unsigned short)(u >> 16);
}
__device__ __forceinline__ float bf2f(unsigned short h) {
    return __uint_as_float(((unsigned int)h) << 16);
}

// ------------------------- CSR build (by dst) ------------------------------
__global__ __launch_bounds__(256) void hist_kernel(const int* __restrict__ dst,
                                                   int* __restrict__ deg) {
    int e = blockIdx.x * 256 + threadIdx.x;
    if (e < N_EDGES) atomicAdd(&deg[dst[e]], 1);
}

__global__ __launch_bounds__(256) void scan_blocks(int* __restrict__ rs,
                                                   int* __restrict__ partials,
                                                   int n) {
    __shared__ int wsum[4];
    int i = blockIdx.x * 256 + threadIdx.x;
    int lane = threadIdx.x & 63;
    int wave = threadIdx.x >> 6;
    int orig = (i < n) ? rs[i] : 0;
    int v = orig;
#pragma unroll
    for (int off = 1; off < 64; off <<= 1) {
        int t = __shfl_up(v, off, 64);
        if (lane >= off) v += t;
    }
    if (lane == 63) wsum[wave] = v;
    __syncthreads();
    int woff = 0;
#pragma unroll
    for (int w = 0; w < 4; ++w)
        if (w < wave) woff += wsum[w];
    int excl = woff + v - orig;
    if (i < n) rs[i] = excl;
    if (threadIdx.x == 255) partials[blockIdx.x] = woff + v;
}

__global__ __launch_bounds__(256) void scan_partials(int* __restrict__ partials,
                                                     int* __restrict__ rs,
                                                     int nb, int n) {
    __shared__ int wsum[4];
    int lane = threadIdx.x & 63;
    int wave = threadIdx.x >> 6;
    int orig = (threadIdx.x < nb) ? partials[threadIdx.x] : 0;
    int v = orig;
#pragma unroll
    for (int off = 1; off < 64; off <<= 1) {
        int t = __shfl_up(v, off, 64);
        if (lane >= off) v += t;
    }
    if (lane == 63) wsum[wave] = v;
    __syncthreads();
    int woff = 0;
#pragma unroll
    for (int w = 0; w < 4; ++w)
        if (w < wave) woff += wsum[w];
    int excl = woff + v - orig;
    if (threadIdx.x < nb) partials[threadIdx.x] = excl;
    if (threadIdx.x == 255) rs[n] = woff + v;
}

__global__ __launch_bounds__(256) void scan_add(int* __restrict__ rs,
                                                const int* __restrict__ partials,
                                                int* __restrict__ cursor, int n) {
    int i = blockIdx.x * 256 + threadIdx.x;
    if (i >= n) return;
    int v = rs[i] + partials[blockIdx.x];
    rs[i] = v;
    cursor[i] = v;
}

__global__ __launch_bounds__(256) void fill_kernel(const int* __restrict__ src,
                                                   const int* __restrict__ dst,
                                                   const float* __restrict__ ew,
                                                   int* __restrict__ cursor,
                                                   int* __restrict__ csr_src,
                                                   float* __restrict__ csr_w) {
    int e = blockIdx.x * 256 + threadIdx.x;
    if (e >= N_EDGES) return;
    int slot = atomicAdd(&cursor[dst[e]], 1);
    csr_src[slot] = src[e];
    csr_w[slot] = ew[e];
}

// ------------- weight cast + transpose: Wt[m][k] = bf16(W[k][m]) -----------
__global__ __launch_bounds__(256) void wt_bf16_t(const float* __restrict__ W,
                                                 short* __restrict__ Wt,
                                                 int K, int M) {
    int idx = blockIdx.x * 256 + threadIdx.x;
    if (idx >= K * M) return;
    int m = idx / K, k = idx - m * K;
    Wt[idx] = (short)f2bf(W[(size_t)k * M + m]);
}

// -------- gather layer1: agg(x) fp32 -> bf16 out, 32 thr/node x 4 feats ----
// Metadata prefetch per 32-edge chunk + 4-edge unroll for MLP.
__global__ __launch_bounds__(256) void gather_x_bf16(const float4* __restrict__ x4,
                                                     const int* __restrict__ rs,
                                                     const int* __restrict__ csr_src,
                                                     const float* __restrict__ csr_w,
                                                     unsigned short* __restrict__ out) {
    int node = blockIdx.x * 8 + (threadIdx.x >> 5);
    int g = threadIdx.x & 31;
    if (node >= N_NODES) return;
    int beg = rs[node], end = rs[node + 1];
    float a0 = 0.f, a1 = 0.f, a2 = 0.f, a3 = 0.f;
    for (int base = beg; base < end; base += 32) {
        int cnt = min(32, end - base);
        int sv = 0; float wv = 0.f;
        if (g < cnt) { sv = csr_src[base + g]; wv = csr_w[base + g]; }
        int j = 0;
        for (; j + 4 <= cnt; j += 4) {
            int s0 = __shfl(sv, j, 32),     s1 = __shfl(sv, j + 1, 32);
            int s2 = __shfl(sv, j + 2, 32), s3 = __shfl(sv, j + 3, 32);
            float w0 = __shfl(wv, j, 32),     w1 = __shfl(wv, j + 1, 32);
            float w2 = __shfl(wv, j + 2, 32), w3 = __shfl(wv, j + 3, 32);
            float4 v0 = x4[(size_t)s0 * 32 + g];
            float4 v1 = x4[(size_t)s1 * 32 + g];
            float4 v2 = x4[(size_t)s2 * 32 + g];
            float4 v3 = x4[(size_t)s3 * 32 + g];
            a0 += v0.x * w0 + v1.x * w1 + v2.x * w2 + v3.x * w3;
            a1 += v0.y * w0 + v1.y * w1 + v2.y * w2 + v3.y * w3;
            a2 += v0.z * w0 + v1.z * w1 + v2.z * w2 + v3.z * w3;
            a3 += v0.w * w0 + v1.w * w1 + v2.w * w2 + v3.w * w3;
        }
        for (; j < cnt; ++j) {
            int s0 = __shfl(sv, j, 32);
            float w0 = __shfl(wv, j, 32);
            float4 v0 = x4[(size_t)s0 * 32 + g];
            a0 += v0.x * w0; a1 += v0.y * w0; a2 += v0.z * w0; a3 += v0.w * w0;
        }
    }
    ushort4 o = make_ushort4(f2bf(a0), f2bf(a1), f2bf(a2), f2bf(a3));
    *(ushort4*)(out + (size_t)node * 128 + g * 4) = o;
}

// ---- gather layer2: agg(h) bf16 -> bias+relu -> bf16, 32 thr/node x 8 -----
__global__ __launch_bounds__(256) void gather_h_bf16(const unsigned short* __restrict__ h,
                                                     const int* __restrict__ rs,
                                                     const int* __restrict__ csr_src,
                                                     const float* __restrict__ csr_w,
                                                     const float* __restrict__ bias,
                                                     unsigned short* __restrict__ out) {
    int node = blockIdx.x * 8 + (threadIdx.x >> 5);
    int g = threadIdx.x & 31;
    if (node >= N_NODES) return;
    int beg = rs[node], end = rs[node + 1];
    float acc[8] = {};
    for (int base = beg; base < end; base += 32) {
        int cnt = min(32, end - base);
        int sv = 0; float wv = 0.f;
        if (g < cnt) { sv = csr_src[base + g]; wv = csr_w[base + g]; }
        int j = 0;
        for (; j + 2 <= cnt; j += 2) {
            int s0 = __shfl(sv, j, 32), s1 = __shfl(sv, j + 1, 32);
            float w0 = __shfl(wv, j, 32), w1 = __shfl(wv, j + 1, 32);
            short8 v0 = *(const short8*)(h + (size_t)s0 * 256 + g * 8);
            short8 v1 = *(const short8*)(h + (size_t)s1 * 256 + g * 8);
#pragma unroll
            for (int t = 0; t < 8; ++t)
                acc[t] += bf2f((unsigned short)v0[t]) * w0 +
                          bf2f((unsigned short)v1[t]) * w1;
        }
        if (j < cnt) {
            int s0 = __shfl(sv, j, 32);
            float w0 = __shfl(wv, j, 32);
            short8 v0 = *(const short8*)(h + (size_t)s0 * 256 + g * 8);
#pragma unroll
            for (int t = 0; t < 8; ++t)
                acc[t] += bf2f((unsigned short)v0[t]) * w0;
        }
    }
    short8 ov;
#pragma unroll
    for (int t = 0; t < 8; ++t) {
        float r = fmaxf(acc[t] + bias[g * 8 + t], 0.f);
        ov[t] = (short)f2bf(r);
    }
    *(short8*)(out + (size_t)node * 256 + g * 8) = ov;
}

// --------------- bf16 MFMA GEMM: C[N,M] = A[N,K] @ Wt[M,K]^T ---------------
template <int OUT_BF16>
__global__ __launch_bounds__(256) void mfma_gemm(const short* __restrict__ A,
                                                 const short* __restrict__ Wt,
                                                 void* __restrict__ Cout,
                                                 int N, int K, int M,
                                                 const float* __restrict__ bias,
                                                 int act) {
    __shared__ short As[128 * 32];
    __shared__ short Bs[64 * 32];
    const int tid = threadIdx.x;
    const int lane = tid & 63;
    const int wave = tid >> 6;
    const int wr = wave >> 1, wc = wave & 1;
    const int row0 = blockIdx.y * 128;
    const int col0 = blockIdx.x * 64;

    floatx4 acc[4][2];
#pragma unroll
    for (int t = 0; t < 4; ++t)
#pragma unroll
        for (int u = 0; u < 2; ++u) acc[t][u] = (floatx4){0.f, 0.f, 0.f, 0.f};

    for (int k0 = 0; k0 < K; k0 += 32) {
#pragma unroll
        for (int i = 0; i < 2; ++i) {
            int idx = tid + i * 256;
            int r = idx >> 2, ch = idx & 3;
            int gr = row0 + r;
            int4 v = make_int4(0, 0, 0, 0);
            if (gr < N) v = *(const int4*)(A + (size_t)gr * K + k0 + ch * 8);
            *(int4*)&As[r * 32 + ((ch ^ ((r >> 1) & 3)) << 3)] = v;
        }
        {
            int r = tid >> 2, ch = tid & 3;
            int gn = col0 + r;
            int4 v = make_int4(0, 0, 0, 0);
            if (gn < M) v = *(const int4*)(Wt + (size_t)gn * K + k0 + ch * 8);
            *(int4*)&Bs[r * 32 + ((ch ^ ((r >> 1) & 3)) << 3)] = v;
        }
        __syncthreads();

        short8 bf[2];
#pragma unroll
        for (int u = 0; u < 2; ++u) {
            int n = wc * 32 + u * 16 + (lane & 15);
            int ch = (lane >> 4) ^ ((n >> 1) & 3);
            bf[u] = *(const short8*)&Bs[n * 32 + (ch << 3)];
        }
#pragma unroll
        for (int t = 0; t < 4; ++t) {
            int r = wr * 64 + t * 16 + (lane & 15);
            int ch = (lane >> 4) ^ ((r >> 1) & 3);
            short8 af = *(const short8*)&As[r * 32 + (ch << 3)];
            acc[t][0] = __builtin_amdgcn_mfma_f32_16x16x32_bf16(af, bf[0], acc[t][0], 0, 0, 0);
            acc[t][1] = __builtin_amdgcn_mfma_f32_16x16x32_bf16(af, bf[1], acc[t][1], 0, 0, 0);
        }
        __syncthreads();
    }

#pragma unroll
    for (int t = 0; t < 4; ++t) {
#pragma unroll
        for (int u = 0; u < 2; ++u) {
            int gcol = col0 + wc * 32 + u * 16 + (lane & 15);
            if (gcol >= M) continue;
            float bv = bias ? bias[gcol] : 0.f;
#pragma unroll
            for (int reg = 0; reg < 4; ++reg) {
                int grow = row0 + wr * 64 + t * 16 + (lane >> 4) * 4 + reg;
                if (grow >= N) continue;
                float v = acc[t][u][reg] + bv;
                if (act) v = fmaxf(v, 0.f);
                if (OUT_BF16)
                    ((unsigned short*)Cout)[(size_t)grow * M + gcol] = f2bf(v);
                else
                    ((float*)Cout)[(size_t)grow * M + gcol] = v;
            }
        }
    }
}

// ---- final: gather 40-wide rows + bias + log_softmax, one wave per node ---
// Metadata prefetch per 64-edge chunk + 4-edge unroll.
__global__ __launch_bounds__(256) void gather_lsm(const float* __restrict__ h,
                                                  const int* __restrict__ rs,
                                                  const int* __restrict__ csr_src,
                                                  const float* __restrict__ csr_w,
                                                  const float* __restrict__ b,
                                                  float* __restrict__ out, int n) {
    int wave = threadIdx.x >> 6;
    int lane = threadIdx.x & 63;
    int node = blockIdx.x * 4 + wave;
    if (node >= n) return;
    int beg = rs[node], end = rs[node + 1];
    float acc = 0.f;
    for (int base = beg; base < end; base += 64) {
        int cnt = min(64, end - base);
        int sv = 0; float wv = 0.f;
        if (lane < cnt) { sv = csr_src[base + lane]; wv = csr_w[base + lane]; }
        int j = 0;
        for (; j + 4 <= cnt; j += 4) {
            int s0 = __shfl(sv, j, 64),     s1 = __shfl(sv, j + 1, 64);
            int s2 = __shfl(sv, j + 2, 64), s3 = __shfl(sv, j + 3, 64);
            float w0 = __shfl(wv, j, 64),     w1 = __shfl(wv, j + 1, 64);
            float w2 = __shfl(wv, j + 2, 64), w3 = __shfl(wv, j + 3, 64);
            float v0 = 0.f, v1 = 0.f, v2 = 0.f, v3 = 0.f;
            if (lane < OUT_CH) {
                v0 = h[(size_t)s0 * OUT_CH + lane];
                v1 = h[(size_t)s1 * OUT_CH + lane];
                v2 = h[(size_t)s2 * OUT_CH + lane];
                v3 = h[(size_t)s3 * OUT_CH + lane];
            }
            acc += v0 * w0 + v1 * w1 + v2 * w2 + v3 * w3;
        }
        for (; j < cnt; ++j) {
            int s0 = __shfl(sv, j, 64);
            float w0 = __shfl(wv, j, 64);
            if (lane < OUT_CH) acc += h[(size_t)s0 * OUT_CH + lane] * w0;
        }
    }
    float val = 0.f, v = -INFINITY;
    if (lane < OUT_CH) {
        val = acc + b[lane];
        v = val;
    }
#pragma unroll
    for (int off = 32; off; off >>= 1)
        v = fmaxf(v, __shfl_xor(v, off, 64));
    float ex = (lane < OUT_CH) ? expf(val - v) : 0.f;
#pragma unroll
    for (int off = 32; off; off >>= 1)
        ex += __shfl_xor(ex, off, 64);
    float ls = logf(ex);
    if (lane < OUT_CH) out[(size_t)node * OUT_CH + lane] = val - v - ls;
}

// ---------------------------------------------------------------------------
extern "C" void kernel_launch(void* const* d_in, const int* in_sizes, int n_in,
                              void* d_out, int out_size, void* d_ws, size_t ws_size,
                              hipStream_t stream) {
    const float* x   = (const float*)d_in[0];
    const int*  eidx = (const int*)d_in[1];
    const float* ew  = (const float*)d_in[2];
    const float* W1  = (const float*)d_in[3];
    const float* b1  = (const float*)d_in[4];
    const float* W2  = (const float*)d_in[5];
    const float* b2  = (const float*)d_in[6];
    const float* W3  = (const float*)d_in[7];
    const float* b3  = (const float*)d_in[8];
    const int* src = eidx;
    const int* dst = eidx + N_EDGES;
    float* out = (float*)d_out;

    short* aggX = (short*)d_ws;                             // 50000*128 bf16
    short* H1   = aggX + (size_t)N_NODES * IN_CH;           // 50000*256 bf16
    short* h2p  = H1   + (size_t)N_NODES * HID;             // 50000*256 bf16
    short* H2   = h2p  + (size_t)N_NODES * HID;             // 50000*256 bf16
    float* h3p  = (float*)(H2 + (size_t)N_NODES * HID);     // 50000*40 fp32
    short* Wt1  = (short*)(h3p + (size_t)N_NODES * OUT_CH); // 256*128 bf16
    short* Wt2  = Wt1 + HID * IN_CH;                        // 256*256 bf16
    short* Wt3  = Wt2 + HID * HID;                          // 40*256 bf16
    int*   rs      = (int*)(Wt3 + OUT_CH * HID);
    int*   cursor  = rs + N_NODES + 2;
    int*   csr_src = cursor + N_NODES;
    float* csr_w   = (float*)(csr_src + N_EDGES);
    int*   partials = (int*)(csr_w + N_EDGES);

    dim3 blk(256);
    const int edge_blocks = (N_EDGES + 255) / 256;
    const int node_blocks = (N_NODES + 255) / 256;

    // ---- CSR build
    hipMemsetAsync(rs, 0, (N_NODES + 1) * sizeof(int), stream);
    hist_kernel<<<edge_blocks, blk, 0, stream>>>(dst, rs);
    scan_blocks<<<node_blocks, blk, 0, stream>>>(rs, partials, N_NODES);
    scan_partials<<<1, blk, 0, stream>>>(partials, rs, node_blocks, N_NODES);
    scan_add<<<node_blocks, blk, 0, stream>>>(rs, partials, cursor, N_NODES);
    fill_kernel<<<edge_blocks, blk, 0, stream>>>(src, dst, ew, cursor, csr_src, csr_w);

    // ---- weight casts
    wt_bf16_t<<<(IN_CH * HID + 255) / 256, blk, 0, stream>>>(W1, Wt1, IN_CH, HID);
    wt_bf16_t<<<(HID * HID + 255) / 256, blk, 0, stream>>>(W2, Wt2, HID, HID);
    wt_bf16_t<<<(HID * OUT_CH + 255) / 256, blk, 0, stream>>>(W3, Wt3, HID, OUT_CH);

    // ---- layer 1 (swapped): aggX = gather(x); H1 = relu(aggX@W1 + b1)
    gather_x_bf16<<<(N_NODES + 7) / 8, blk, 0, stream>>>(
        (const float4*)x, rs, csr_src, csr_w, (unsigned short*)aggX);
    {
        dim3 grid((HID + 63) / 64, (N_NODES + 127) / 128);
        mfma_gemm<1><<<grid, blk, 0, stream>>>(aggX, Wt1, H1, N_NODES, IN_CH, HID, b1, 1);
    }

    // ---- layer 2: h2p = H1@W2 ; H2 = relu(gather(h2p) + b2)
    {
        dim3 grid((HID + 63) / 64, (N_NODES + 127) / 128);
        mfma_gemm<1><<<grid, blk, 0, stream>>>(H1, Wt2, h2p, N_NODES, HID, HID, nullptr, 0);
    }
    gather_h_bf16<<<(N_NODES + 7) / 8, blk, 0, stream>>>(
        (const unsigned short*)h2p, rs, csr_src, csr_w, b2, (unsigned short*)H2);

    // ---- layer 3: h3p = H2@W3 ; out = log_softmax(gather(h3p) + b3)
    {
        dim3 grid((OUT_CH + 63) / 64, (N_NODES + 127) / 128);
        mfma_gemm<0><<<grid, blk, 0, stream>>>(H2, Wt3, h3p, N_NODES, HID, OUT_CH, nullptr, 0);
    }
    gather_lsm<<<(N_NODES + 3) / 4, blk, 0, stream>>>(h3p, rs, csr_src, csr_w, b3, out, N_NODES);
}

// Round 6
// 361.515 us; speedup vs baseline: 16.9727x; 1.0857x over previous
//
#include <hip/hip_runtime.h>
#include <math.h>

#define N_NODES 50000
#define N_EDGES 800000
#define IN_CH 128
#define HID 256
#define OUT_CH 40

typedef __attribute__((ext_vector_type(8))) short short8;
typedef __attribute__((ext_vector_type(4))) float floatx4;

__device__ __forceinline__ unsigned short f2bf(float f) {
    unsigned int u = __float_as_uint(f);
    u += 0x7fff + ((u >> 16) & 1);
    return (unsigned short)(u >> 16);
}
__device__ __forceinline__ float bf2f(unsigned short h) {
    return __uint_as_float(((unsigned int)h) << 16);
}

// ------------------------- CSR build (by dst) ------------------------------
__global__ __launch_bounds__(256) void hist_kernel(const int* __restrict__ dst,
                                                   int* __restrict__ deg) {
    int e = blockIdx.x * 256 + threadIdx.x;
    if (e < N_EDGES) atomicAdd(&deg[dst[e]], 1);
}

__global__ __launch_bounds__(256) void scan_blocks(int* __restrict__ rs,
                                                   int* __restrict__ partials,
                                                   int n) {
    __shared__ int wsum[4];
    int i = blockIdx.x * 256 + threadIdx.x;
    int lane = threadIdx.x & 63;
    int wave = threadIdx.x >> 6;
    int orig = (i < n) ? rs[i] : 0;
    int v = orig;
#pragma unroll
    for (int off = 1; off < 64; off <<= 1) {
        int t = __shfl_up(v, off, 64);
        if (lane >= off) v += t;
    }
    if (lane == 63) wsum[wave] = v;
    __syncthreads();
    int woff = 0;
#pragma unroll
    for (int w = 0; w < 4; ++w)
        if (w < wave) woff += wsum[w];
    int excl = woff + v - orig;
    if (i < n) rs[i] = excl;
    if (threadIdx.x == 255) partials[blockIdx.x] = woff + v;
}

__global__ __launch_bounds__(256) void scan_partials(int* __restrict__ partials,
                                                     int* __restrict__ rs,
                                                     int nb, int n) {
    __shared__ int wsum[4];
    int lane = threadIdx.x & 63;
    int wave = threadIdx.x >> 6;
    int orig = (threadIdx.x < nb) ? partials[threadIdx.x] : 0;
    int v = orig;
#pragma unroll
    for (int off = 1; off < 64; off <<= 1) {
        int t = __shfl_up(v, off, 64);
        if (lane >= off) v += t;
    }
    if (lane == 63) wsum[wave] = v;
    __syncthreads();
    int woff = 0;
#pragma unroll
    for (int w = 0; w < 4; ++w)
        if (w < wave) woff += wsum[w];
    int excl = woff + v - orig;
    if (threadIdx.x < nb) partials[threadIdx.x] = excl;
    if (threadIdx.x == 255) rs[n] = woff + v;
}

__global__ __launch_bounds__(256) void scan_add(int* __restrict__ rs,
                                                const int* __restrict__ partials,
                                                int* __restrict__ cursor, int n) {
    int i = blockIdx.x * 256 + threadIdx.x;
    if (i >= n) return;
    int v = rs[i] + partials[blockIdx.x];
    rs[i] = v;
    cursor[i] = v;
}

// one 8B interleaved store per edge: csr[slot] = {src, bits(w)}
__global__ __launch_bounds__(256) void fill_kernel(const int* __restrict__ src,
                                                   const int* __restrict__ dst,
                                                   const float* __restrict__ ew,
                                                   int* __restrict__ cursor,
                                                   int2* __restrict__ csr) {
    int e = blockIdx.x * 256 + threadIdx.x;
    if (e >= N_EDGES) return;
    int slot = atomicAdd(&cursor[dst[e]], 1);
    csr[slot] = make_int2(src[e], __float_as_int(ew[e]));
}

// ------------- weight cast + transpose: Wt[m][k] = bf16(W[k][m]) -----------
__global__ __launch_bounds__(256) void wt_bf16_t(const float* __restrict__ W,
                                                 short* __restrict__ Wt,
                                                 int K, int M) {
    int idx = blockIdx.x * 256 + threadIdx.x;
    if (idx >= K * M) return;
    int m = idx / K, k = idx - m * K;
    Wt[idx] = (short)f2bf(W[(size_t)k * M + m]);
}

// ------------------- x cast fp32 -> bf16 (sequential) ----------------------
__global__ __launch_bounds__(256) void cast_x_bf16(const float4* __restrict__ x4,
                                                   ushort4* __restrict__ xb,
                                                   int total4) {
    int i = blockIdx.x * 256 + threadIdx.x;
    if (i >= total4) return;
    float4 v = x4[i];
    xb[i] = make_ushort4(f2bf(v.x), f2bf(v.y), f2bf(v.z), f2bf(v.w));
}

// -------- gather layer1: agg(xb bf16) -> bf16, 32 thr/node x 4 feats -------
__global__ __launch_bounds__(256) void gather_x_bf16(const unsigned short* __restrict__ xb,
                                                     const int* __restrict__ rs,
                                                     const int2* __restrict__ csr,
                                                     unsigned short* __restrict__ out) {
    int node = blockIdx.x * 8 + (threadIdx.x >> 5);
    int g = threadIdx.x & 31;
    if (node >= N_NODES) return;
    int beg = rs[node], end = rs[node + 1];
    float a0 = 0.f, a1 = 0.f, a2 = 0.f, a3 = 0.f;
    for (int base = beg; base < end; base += 32) {
        int cnt = min(32, end - base);
        int sv = 0; float wv = 0.f;
        if (g < cnt) {
            int2 iv = csr[base + g];
            sv = iv.x; wv = __int_as_float(iv.y);
        }
        int j = 0;
        for (; j + 4 <= cnt; j += 4) {
            int s0 = __shfl(sv, j, 32),     s1 = __shfl(sv, j + 1, 32);
            int s2 = __shfl(sv, j + 2, 32), s3 = __shfl(sv, j + 3, 32);
            float w0 = __shfl(wv, j, 32),     w1 = __shfl(wv, j + 1, 32);
            float w2 = __shfl(wv, j + 2, 32), w3 = __shfl(wv, j + 3, 32);
            ushort4 v0 = *(const ushort4*)(xb + (size_t)s0 * 128 + g * 4);
            ushort4 v1 = *(const ushort4*)(xb + (size_t)s1 * 128 + g * 4);
            ushort4 v2 = *(const ushort4*)(xb + (size_t)s2 * 128 + g * 4);
            ushort4 v3 = *(const ushort4*)(xb + (size_t)s3 * 128 + g * 4);
            a0 += bf2f(v0.x) * w0 + bf2f(v1.x) * w1 + bf2f(v2.x) * w2 + bf2f(v3.x) * w3;
            a1 += bf2f(v0.y) * w0 + bf2f(v1.y) * w1 + bf2f(v2.y) * w2 + bf2f(v3.y) * w3;
            a2 += bf2f(v0.z) * w0 + bf2f(v1.z) * w1 + bf2f(v2.z) * w2 + bf2f(v3.z) * w3;
            a3 += bf2f(v0.w) * w0 + bf2f(v1.w) * w1 + bf2f(v2.w) * w2 + bf2f(v3.w) * w3;
        }
        for (; j < cnt; ++j) {
            int s0 = __shfl(sv, j, 32);
            float w0 = __shfl(wv, j, 32);
            ushort4 v0 = *(const ushort4*)(xb + (size_t)s0 * 128 + g * 4);
            a0 += bf2f(v0.x) * w0; a1 += bf2f(v0.y) * w0;
            a2 += bf2f(v0.z) * w0; a3 += bf2f(v0.w) * w0;
        }
    }
    ushort4 o = make_ushort4(f2bf(a0), f2bf(a1), f2bf(a2), f2bf(a3));
    *(ushort4*)(out + (size_t)node * 128 + g * 4) = o;
}

// ---- gather layer2: agg(h) bf16 -> bias+relu -> bf16, 32 thr/node x 8 -----
__global__ __launch_bounds__(256) void gather_h_bf16(const unsigned short* __restrict__ h,
                                                     const int* __restrict__ rs,
                                                     const int2* __restrict__ csr,
                                                     const float* __restrict__ bias,
                                                     unsigned short* __restrict__ out) {
    int node = blockIdx.x * 8 + (threadIdx.x >> 5);
    int g = threadIdx.x & 31;
    if (node >= N_NODES) return;
    int beg = rs[node], end = rs[node + 1];
    float acc[8] = {};
    for (int base = beg; base < end; base += 32) {
        int cnt = min(32, end - base);
        int sv = 0; float wv = 0.f;
        if (g < cnt) {
            int2 iv = csr[base + g];
            sv = iv.x; wv = __int_as_float(iv.y);
        }
        int j = 0;
        for (; j + 2 <= cnt; j += 2) {
            int s0 = __shfl(sv, j, 32), s1 = __shfl(sv, j + 1, 32);
            float w0 = __shfl(wv, j, 32), w1 = __shfl(wv, j + 1, 32);
            short8 v0 = *(const short8*)(h + (size_t)s0 * 256 + g * 8);
            short8 v1 = *(const short8*)(h + (size_t)s1 * 256 + g * 8);
#pragma unroll
            for (int t = 0; t < 8; ++t)
                acc[t] += bf2f((unsigned short)v0[t]) * w0 +
                          bf2f((unsigned short)v1[t]) * w1;
        }
        if (j < cnt) {
            int s0 = __shfl(sv, j, 32);
            float w0 = __shfl(wv, j, 32);
            short8 v0 = *(const short8*)(h + (size_t)s0 * 256 + g * 8);
#pragma unroll
            for (int t = 0; t < 8; ++t)
                acc[t] += bf2f((unsigned short)v0[t]) * w0;
        }
    }
    short8 ov;
#pragma unroll
    for (int t = 0; t < 8; ++t) {
        float r = fmaxf(acc[t] + bias[g * 8 + t], 0.f);
        ov[t] = (short)f2bf(r);
    }
    *(short8*)(out + (size_t)node * 256 + g * 8) = ov;
}

// --------------- bf16 MFMA GEMM: C[N,M] = A[N,K] @ Wt[M,K]^T ---------------
template <int OUT_BF16>
__global__ __launch_bounds__(256) void mfma_gemm(const short* __restrict__ A,
                                                 const short* __restrict__ Wt,
                                                 void* __restrict__ Cout,
                                                 int N, int K, int M,
                                                 const float* __restrict__ bias,
                                                 int act) {
    __shared__ short As[128 * 32];
    __shared__ short Bs[64 * 32];
    const int tid = threadIdx.x;
    const int lane = tid & 63;
    const int wave = tid >> 6;
    const int wr = wave >> 1, wc = wave & 1;
    const int row0 = blockIdx.y * 128;
    const int col0 = blockIdx.x * 64;

    floatx4 acc[4][2];
#pragma unroll
    for (int t = 0; t < 4; ++t)
#pragma unroll
        for (int u = 0; u < 2; ++u) acc[t][u] = (floatx4){0.f, 0.f, 0.f, 0.f};

    for (int k0 = 0; k0 < K; k0 += 32) {
#pragma unroll
        for (int i = 0; i < 2; ++i) {
            int idx = tid + i * 256;
            int r = idx >> 2, ch = idx & 3;
            int gr = row0 + r;
            int4 v = make_int4(0, 0, 0, 0);
            if (gr < N) v = *(const int4*)(A + (size_t)gr * K + k0 + ch * 8);
            *(int4*)&As[r * 32 + ((ch ^ ((r >> 1) & 3)) << 3)] = v;
        }
        {
            int r = tid >> 2, ch = tid & 3;
            int gn = col0 + r;
            int4 v = make_int4(0, 0, 0, 0);
            if (gn < M) v = *(const int4*)(Wt + (size_t)gn * K + k0 + ch * 8);
            *(int4*)&Bs[r * 32 + ((ch ^ ((r >> 1) & 3)) << 3)] = v;
        }
        __syncthreads();

        short8 bf[2];
#pragma unroll
        for (int u = 0; u < 2; ++u) {
            int n = wc * 32 + u * 16 + (lane & 15);
            int ch = (lane >> 4) ^ ((n >> 1) & 3);
            bf[u] = *(const short8*)&Bs[n * 32 + (ch << 3)];
        }
#pragma unroll
        for (int t = 0; t < 4; ++t) {
            int r = wr * 64 + t * 16 + (lane & 15);
            int ch = (lane >> 4) ^ ((r >> 1) & 3);
            short8 af = *(const short8*)&As[r * 32 + (ch << 3)];
            acc[t][0] = __builtin_amdgcn_mfma_f32_16x16x32_bf16(af, bf[0], acc[t][0], 0, 0, 0);
            acc[t][1] = __builtin_amdgcn_mfma_f32_16x16x32_bf16(af, bf[1], acc[t][1], 0, 0, 0);
        }
        __syncthreads();
    }

#pragma unroll
    for (int t = 0; t < 4; ++t) {
#pragma unroll
        for (int u = 0; u < 2; ++u) {
            int gcol = col0 + wc * 32 + u * 16 + (lane & 15);
            if (gcol >= M) continue;
            float bv = bias ? bias[gcol] : 0.f;
#pragma unroll
            for (int reg = 0; reg < 4; ++reg) {
                int grow = row0 + wr * 64 + t * 16 + (lane >> 4) * 4 + reg;
                if (grow >= N) continue;
                float v = acc[t][u][reg] + bv;
                if (act) v = fmaxf(v, 0.f);
                if (OUT_BF16)
                    ((unsigned short*)Cout)[(size_t)grow * M + gcol] = f2bf(v);
                else
                    ((float*)Cout)[(size_t)grow * M + gcol] = v;
            }
        }
    }
}

// ---- final: gather bf16 40-wide rows + bias + log_softmax, wave/node ------
__global__ __launch_bounds__(256) void gather_lsm(const unsigned short* __restrict__ h,
                                                  const int* __restrict__ rs,
                                                  const int2* __restrict__ csr,
                                                  const float* __restrict__ b,
                                                  float* __restrict__ out, int n) {
    int wave = threadIdx.x >> 6;
    int lane = threadIdx.x & 63;
    int node = blockIdx.x * 4 + wave;
    if (node >= n) return;
    int beg = rs[node], end = rs[node + 1];
    float acc = 0.f;
    for (int base = beg; base < end; base += 64) {
        int cnt = min(64, end - base);
        int sv = 0; float wv = 0.f;
        if (lane < cnt) {
            int2 iv = csr[base + lane];
            sv = iv.x; wv = __int_as_float(iv.y);
        }
        int j = 0;
        for (; j + 4 <= cnt; j += 4) {
            int s0 = __shfl(sv, j, 64),     s1 = __shfl(sv, j + 1, 64);
            int s2 = __shfl(sv, j + 2, 64), s3 = __shfl(sv, j + 3, 64);
            float w0 = __shfl(wv, j, 64),     w1 = __shfl(wv, j + 1, 64);
            float w2 = __shfl(wv, j + 2, 64), w3 = __shfl(wv, j + 3, 64);
            float v0 = 0.f, v1 = 0.f, v2 = 0.f, v3 = 0.f;
            if (lane < OUT_CH) {
                v0 = bf2f(h[(size_t)s0 * OUT_CH + lane]);
                v1 = bf2f(h[(size_t)s1 * OUT_CH + lane]);
                v2 = bf2f(h[(size_t)s2 * OUT_CH + lane]);
                v3 = bf2f(h[(size_t)s3 * OUT_CH + lane]);
            }
            acc += v0 * w0 + v1 * w1 + v2 * w2 + v3 * w3;
        }
        for (; j < cnt; ++j) {
            int s0 = __shfl(sv, j, 64);
            float w0 = __shfl(wv, j, 64);
            if (lane < OUT_CH) acc += bf2f(h[(size_t)s0 * OUT_CH + lane]) * w0;
        }
    }
    float val = 0.f, v = -INFINITY;
    if (lane < OUT_CH) {
        val = acc + b[lane];
        v = val;
    }
#pragma unroll
    for (int off = 32; off; off >>= 1)
        v = fmaxf(v, __shfl_xor(v, off, 64));
    float ex = (lane < OUT_CH) ? expf(val - v) : 0.f;
#pragma unroll
    for (int off = 32; off; off >>= 1)
        ex += __shfl_xor(ex, off, 64);
    float ls = logf(ex);
    if (lane < OUT_CH) out[(size_t)node * OUT_CH + lane] = val - v - ls;
}

// ---------------------------------------------------------------------------
extern "C" void kernel_launch(void* const* d_in, const int* in_sizes, int n_in,
                              void* d_out, int out_size, void* d_ws, size_t ws_size,
                              hipStream_t stream) {
    const float* x   = (const float*)d_in[0];
    const int*  eidx = (const int*)d_in[1];
    const float* ew  = (const float*)d_in[2];
    const float* W1  = (const float*)d_in[3];
    const float* b1  = (const float*)d_in[4];
    const float* W2  = (const float*)d_in[5];
    const float* b2  = (const float*)d_in[6];
    const float* W3  = (const float*)d_in[7];
    const float* b3  = (const float*)d_in[8];
    const int* src = eidx;
    const int* dst = eidx + N_EDGES;
    float* out = (float*)d_out;

    // ---- workspace layout (aliased by lifetime) ----
    // region0 (50000*256 bf16): xbf (first half, dies after gather_x) / h2p
    // region1 (50000*128 bf16): aggX (dies after gemm1) / h3p (50000*40 bf16)
    short* region0 = (short*)d_ws;
    short* region1 = region0 + (size_t)N_NODES * HID;
    short* H1   = region1 + (size_t)N_NODES * IN_CH;        // 50000*256 bf16
    short* H2   = H1 + (size_t)N_NODES * HID;               // 50000*256 bf16
    short* Wt1  = H2 + (size_t)N_NODES * HID;               // 256*128
    short* Wt2  = Wt1 + HID * IN_CH;                        // 256*256
    short* Wt3  = Wt2 + HID * HID;                          // 40*256
    int*   rs      = (int*)(Wt3 + OUT_CH * HID);
    int*   cursor  = rs + N_NODES + 2;
    int2*  csr     = (int2*)(cursor + N_NODES);             // 800000 int2
    int*   partials = (int*)(csr + N_EDGES);

    short* xbf  = region0;
    short* h2p  = region0;
    short* aggX = region1;
    short* h3p  = region1;

    dim3 blk(256);
    const int edge_blocks = (N_EDGES + 255) / 256;
    const int node_blocks = (N_NODES + 255) / 256;

    // ---- CSR build
    hipMemsetAsync(rs, 0, (N_NODES + 1) * sizeof(int), stream);
    hist_kernel<<<edge_blocks, blk, 0, stream>>>(dst, rs);
    scan_blocks<<<node_blocks, blk, 0, stream>>>(rs, partials, N_NODES);
    scan_partials<<<1, blk, 0, stream>>>(partials, rs, node_blocks, N_NODES);
    scan_add<<<node_blocks, blk, 0, stream>>>(rs, partials, cursor, N_NODES);
    fill_kernel<<<edge_blocks, blk, 0, stream>>>(src, dst, ew, cursor, csr);

    // ---- weight + x casts
    wt_bf16_t<<<(IN_CH * HID + 255) / 256, blk, 0, stream>>>(W1, Wt1, IN_CH, HID);
    wt_bf16_t<<<(HID * HID + 255) / 256, blk, 0, stream>>>(W2, Wt2, HID, HID);
    wt_bf16_t<<<(HID * OUT_CH + 255) / 256, blk, 0, stream>>>(W3, Wt3, HID, OUT_CH);
    cast_x_bf16<<<(N_NODES * IN_CH / 4 + 255) / 256, blk, 0, stream>>>(
        (const float4*)x, (ushort4*)xbf, N_NODES * IN_CH / 4);

    // ---- layer 1 (swapped): aggX = gather(xbf); H1 = relu(aggX@W1 + b1)
    gather_x_bf16<<<(N_NODES + 7) / 8, blk, 0, stream>>>(
        (const unsigned short*)xbf, rs, csr, (unsigned short*)aggX);
    {
        dim3 grid((HID + 63) / 64, (N_NODES + 127) / 128);
        mfma_gemm<1><<<grid, blk, 0, stream>>>(aggX, Wt1, H1, N_NODES, IN_CH, HID, b1, 1);
    }

    // ---- layer 2: h2p = H1@W2 ; H2 = relu(gather(h2p) + b2)
    {
        dim3 grid((HID + 63) / 64, (N_NODES + 127) / 128);
        mfma_gemm<1><<<grid, blk, 0, stream>>>(H1, Wt2, h2p, N_NODES, HID, HID, nullptr, 0);
    }
    gather_h_bf16<<<(N_NODES + 7) / 8, blk, 0, stream>>>(
        (const unsigned short*)h2p, rs, csr, b2, (unsigned short*)H2);

    // ---- layer 3: h3p = H2@W3 (bf16) ; out = log_softmax(gather(h3p) + b3)
    {
        dim3 grid((OUT_CH + 63) / 64, (N_NODES + 127) / 128);
        mfma_gemm<1><<<grid, blk, 0, stream>>>(H2, Wt3, h3p, N_NODES, HID, OUT_CH, nullptr, 0);
    }
    gather_lsm<<<(N_NODES + 3) / 4, blk, 0, stream>>>(
        (const unsigned short*)h3p, rs, csr, b3, out, N_NODES);
}